// Round 6
// baseline (402.540 us; speedup 1.0000x reference)
//
#include <hip/hip_runtime.h>
#include <hip/hip_bf16.h>
#include <math.h>

#define NB    64          // number of segments (B)
#define CD    512         // channels C
#define CV    128         // C / 4 (float4 per row)
#define MIDD  2048        // 4*C
#define RS    64          // row-splits per segment in pass 1
#define EPSV  1e-5f
#define FPT   8           // float4 per thread in k_final

typedef float fx4 __attribute__((ext_vector_type(4)));

__device__ __forceinline__ float wave_sum64(float x) {
    #pragma unroll
    for (int o = 32; o; o >>= 1) x += __shfl_xor(x, o, 64);
    return x;
}

__device__ __forceinline__ int seg_search(const int* __restrict__ cum, int row) {
    int lo = 0, hi = NB - 1;
    while (lo < hi) {
        int mid = (lo + hi) >> 1;
        if (cum[mid] > row) hi = mid; else lo = mid + 1;
    }
    return lo;
}

// ---------------- Pass 1: per-segment partial sums ----------------
// grid = NB*RS blocks, 128 threads (thread = float4 column)
__global__ __launch_bounds__(128) void k_partial(const float* __restrict__ x2,
                          const int* __restrict__ npoint,
                          float* __restrict__ P) {
    int bx = blockIdx.x;
    int b  = bx >> 6;            // / RS
    int rs = bx & (RS - 1);
    int start = 0;
    for (int i = 0; i < b; ++i) start += npoint[i];
    int len   = npoint[b];
    int chunk = (len + RS - 1) / RS;
    int r0 = rs * chunk;
    int r1 = min(r0 + chunk, len);
    int t = threadIdx.x;
    const float4* xv = (const float4*)x2;
    float4 acc = make_float4(0.f, 0.f, 0.f, 0.f);
    #pragma unroll 8
    for (int r = r0; r < r1; ++r) {
        float4 v = xv[(size_t)(start + r) * CV + t];
        acc.x += v.x; acc.y += v.y; acc.z += v.z; acc.w += v.w;
    }
    ((float4*)P)[(size_t)bx * CV + t] = acc;
}

// ---------------- Pass 1b: reduce partials -> mean_t (transposed [C][NB]), cum ----------------
// grid = NB blocks, 128 threads
__global__ __launch_bounds__(128) void k_mean(const float* __restrict__ P,
                       const int* __restrict__ npoint,
                       float* __restrict__ mean_t,
                       int* __restrict__ cum) {
    int b = blockIdx.x;
    int t = threadIdx.x;
    const float4* Pv = (const float4*)P;
    float4 acc = make_float4(0.f, 0.f, 0.f, 0.f);
    #pragma unroll 8
    for (int rs = 0; rs < RS; ++rs) {
        float4 v = Pv[((size_t)(b * RS + rs)) * CV + t];
        acc.x += v.x; acc.y += v.y; acc.z += v.z; acc.w += v.w;
    }
    float inv = 1.0f / (float)npoint[b];
    int c = 4 * t;
    mean_t[(size_t)(c + 0) * NB + b] = acc.x * inv;
    mean_t[(size_t)(c + 1) * NB + b] = acc.y * inv;
    mean_t[(size_t)(c + 2) * NB + b] = acc.z * inv;
    mean_t[(size_t)(c + 3) * NB + b] = acc.w * inv;
    if (t == 0) {
        int s = 0;
        for (int i = 0; i <= b; ++i) s += npoint[i];
        cum[b] = s;
    }
}

// ---------------- FC1 + BN + ReLU (both branches), 8-way K-split ----------------
// grid = 2 * (MIDD/8) = 512 blocks, 512 threads (8 waves; lane = batch row)
__global__ __launch_bounds__(512) void k_fc1(const float* __restrict__ mean_t,
                                             const float* __restrict__ W1a,
                                             const float* __restrict__ g1a,
                                             const float* __restrict__ b1a,
                                             const float* __restrict__ W1b,
                                             const float* __restrict__ g1b,
                                             const float* __restrict__ b1b,
                                             float* __restrict__ h_t) {
    __shared__ float red[8][64][9];
    int bx = blockIdx.x;
    int branch = bx >> 8;            // 256 col-groups per branch
    int cg = bx & 255;
    int c0 = cg * 8;
    const float* W1 = branch ? W1b : W1a;
    const float* g  = branch ? g1b : g1a;
    const float* bb = branch ? b1b : b1a;
    int t = threadIdx.x;
    int lane = t & 63;               // batch row
    int w = t >> 6;                  // wave id = K-chunk = epilogue column
    float acc[8];
    #pragma unroll
    for (int i = 0; i < 8; ++i) acc[i] = 0.f;
    int k0 = w * 64;
    for (int k = k0; k < k0 + 64; ++k) {
        float mval = mean_t[(size_t)k * NB + lane];           // coalesced
        const float4* wr = (const float4*)(W1 + (size_t)k * MIDD + c0);
        float4 w0 = wr[0], w1 = wr[1];                        // broadcast
        acc[0] += mval * w0.x; acc[1] += mval * w0.y;
        acc[2] += mval * w0.z; acc[3] += mval * w0.w;
        acc[4] += mval * w1.x; acc[5] += mval * w1.y;
        acc[6] += mval * w1.z; acc[7] += mval * w1.w;
    }
    #pragma unroll
    for (int i = 0; i < 8; ++i) red[w][lane][i] = acc[i];
    __syncthreads();
    // epilogue: wave w owns column c0+w
    float v = red[0][lane][w];
    #pragma unroll
    for (int ww = 1; ww < 8; ++ww) v += red[ww][lane][w];
    float s = wave_sum64(v);
    float m = s * (1.0f / 64.0f);
    float d = v - m;
    float q = wave_sum64(d * d);
    float var = q * (1.0f / 64.0f);
    float val = fmaxf(d * rsqrtf(var + EPSV) * g[c0 + w] + bb[c0 + w], 0.0f);
    h_t[((size_t)branch * MIDD + c0 + w) * NB + lane] = val;  // coalesced
}

// ---------------- FC2 (+ReLU, +sigmoid for branch b), 8-way K-split ----------------
// grid = 2 * (CD/8) = 128 blocks, 512 threads
__global__ __launch_bounds__(512) void k_fc2(const float* __restrict__ h_t,
                                             const float* __restrict__ W2a,
                                             const float* __restrict__ W2b,
                                             float* __restrict__ out_mean,
                                             float* __restrict__ out_w) {
    __shared__ float red[8][64][9];
    int bx = blockIdx.x;
    int branch = bx >> 6;            // 64 col-groups per branch
    int cg = bx & 63;
    int c0 = cg * 8;
    const float* W2 = branch ? W2b : W2a;
    int t = threadIdx.x;
    int lane = t & 63;
    int w = t >> 6;
    float acc[8];
    #pragma unroll
    for (int i = 0; i < 8; ++i) acc[i] = 0.f;
    int k0 = w * 256;
    for (int k = k0; k < k0 + 256; ++k) {
        float hv = h_t[((size_t)branch * MIDD + k) * NB + lane];   // coalesced
        const float4* wr = (const float4*)(W2 + (size_t)k * CD + c0);
        float4 w0 = wr[0], w1 = wr[1];                             // broadcast
        acc[0] += hv * w0.x; acc[1] += hv * w0.y;
        acc[2] += hv * w0.z; acc[3] += hv * w0.w;
        acc[4] += hv * w1.x; acc[5] += hv * w1.y;
        acc[6] += hv * w1.z; acc[7] += hv * w1.w;
    }
    #pragma unroll
    for (int i = 0; i < 8; ++i) red[w][lane][i] = acc[i];
    __syncthreads();
    float v = red[0][lane][w];
    #pragma unroll
    for (int ww = 1; ww < 8; ++ww) v += red[ww][lane][w];
    float r = fmaxf(v, 0.0f);
    if (branch)
        out_w[(size_t)lane * CD + c0 + w] = 1.0f / (1.0f + expf(-r));
    else
        out_mean[(size_t)lane * CD + c0 + w] = r;
}

// ---------------- Final combine: memcpy-like. 512 thr x 8 float4 = 64KB/block ----------------
// forward order, plain loads AND plain stores (nt falsified rounds 4/5)
__global__ __launch_bounds__(512) void k_final(const float* __restrict__ x2,
                        const int* __restrict__ cum,
                        const float* __restrict__ out_mean,
                        const float* __restrict__ out_w,
                        float* __restrict__ out) {
    int t = threadIdx.x;
    int bx = blockIdx.x;
    size_t base = (size_t)bx << 12;                   // 4096 float4 per block
    int base_row = bx << 5;                           // 32 rows per block
    const fx4* xv = (const fx4*)x2;
    const fx4* wv = (const fx4*)out_w;
    const fx4* mv = (const fx4*)out_mean;
    fx4* ov = (fx4*)out;

    // issue all 8 x2 loads first (independent of the search)
    fx4 xs[FPT];
    #pragma unroll
    for (int k = 0; k < FPT; ++k)
        xs[k] = xv[base + ((size_t)k << 9) + t];

    int seg_lo = seg_search(cum, base_row);
    int seg_hi = seg_search(cum, base_row + 31);
    int colv = t & 127;

    if (seg_lo == seg_hi) {          // block-uniform branch (common case)
        fx4 ww = wv[(size_t)seg_lo * CV + colv];
        fx4 mm = mv[(size_t)seg_lo * CV + colv];
        fx4 a = ww * 0.5f + 0.75f;
        #pragma unroll
        for (int k = 0; k < FPT; ++k) {
            ov[base + ((size_t)k << 9) + t] = xs[k] * a + mm;
        }
    } else {                          // rare: block straddles a segment boundary
        #pragma unroll
        for (int k = 0; k < FPT; ++k) {
            int row = base_row + ((k * 512 + t) >> 7);
            int seg = seg_search(cum, row);
            fx4 ww = wv[(size_t)seg * CV + colv];
            fx4 mm = mv[(size_t)seg * CV + colv];
            ov[base + ((size_t)k << 9) + t] = xs[k] * (ww * 0.5f + 0.75f) + mm;
        }
    }
}

extern "C" void kernel_launch(void* const* d_in, const int* in_sizes, int n_in,
                              void* d_out, int out_size, void* d_ws, size_t ws_size,
                              hipStream_t stream) {
    const float* x2  = (const float*)d_in[0];
    const int*   npt = (const int*)d_in[1];
    const float* W1a = (const float*)d_in[2];
    const float* g1a = (const float*)d_in[3];
    const float* b1a = (const float*)d_in[4];
    const float* W2a = (const float*)d_in[5];
    const float* W1b = (const float*)d_in[6];
    const float* g1b = (const float*)d_in[7];
    const float* b1b = (const float*)d_in[8];
    const float* W2b = (const float*)d_in[9];
    float* out = (float*)d_out;

    const int N   = in_sizes[0] / CD;      // 262144
    const int NC4 = (N * CD) / 4;          // total float4

    // scratch: big dead-before-final arrays live in d_out
    float* P      = out;                              // [NB*RS*CD]    = 8 MB
    float* mean_t = out + (size_t)NB * RS * CD;       // [CD*NB]       = 128 KB (transposed)
    float* h_t    = mean_t + (size_t)NB * CD;         // [2*MIDD*NB]   = 1 MB (transposed)
    // small live-at-final arrays in ws
    int*   cum      = (int*)d_ws;                     // 64 ints
    float* out_mean = (float*)d_ws + 64;              // [NB*CD]
    float* out_w    = out_mean + (size_t)NB * CD;     // [NB*CD]

    k_partial<<<NB * RS, 128, 0, stream>>>(x2, npt, P);
    k_mean<<<NB, 128, 0, stream>>>(P, npt, mean_t, cum);
    k_fc1<<<2 * (MIDD / 8), 512, 0, stream>>>(mean_t, W1a, g1a, b1a, W1b, g1b, b1b, h_t);
    k_fc2<<<2 * (CD / 8), 512, 0, stream>>>(h_t, W2a, W2b, out_mean, out_w);
    k_final<<<NC4 / (512 * FPT), 512, 0, stream>>>(x2, cum, out_mean, out_w, out);
}

// Round 7
// 365.249 us; speedup vs baseline: 1.1021x; 1.1021x over previous
//
#include <hip/hip_runtime.h>
#include <hip/hip_bf16.h>
#include <math.h>

#define NB    64          // number of segments (B)
#define CD    512         // channels C
#define CV    128         // C / 4 (float4 per row)
#define MIDD  2048        // 4*C
#define RS    64          // row-splits per segment in pass 1
#define EPSV  1e-5f
#define FPT   8           // float4 per thread in k_final
#define FROWS 16          // rows per k_final block (256 thr * 8 fp4 / 128)

typedef float fx4 __attribute__((ext_vector_type(4)));

__device__ __forceinline__ float wave_sum64(float x) {
    #pragma unroll
    for (int o = 32; o; o >>= 1) x += __shfl_xor(x, o, 64);
    return x;
}

__device__ __forceinline__ int seg_search(const int* __restrict__ cum, int row) {
    int lo = 0, hi = NB - 1;
    while (lo < hi) {
        int mid = (lo + hi) >> 1;
        if (cum[mid] > row) hi = mid; else lo = mid + 1;
    }
    return lo;
}

// ---------------- Pass 1: per-segment partial sums ----------------
// grid = NB*RS blocks, 128 threads (thread = float4 column)
__global__ __launch_bounds__(128) void k_partial(const float* __restrict__ x2,
                          const int* __restrict__ npoint,
                          float* __restrict__ P) {
    int bx = blockIdx.x;
    int b  = bx >> 6;            // / RS
    int rs = bx & (RS - 1);
    int start = 0;
    for (int i = 0; i < b; ++i) start += npoint[i];
    int len   = npoint[b];
    int chunk = (len + RS - 1) / RS;
    int r0 = rs * chunk;
    int r1 = min(r0 + chunk, len);
    int t = threadIdx.x;
    const float4* xv = (const float4*)x2;
    float4 acc = make_float4(0.f, 0.f, 0.f, 0.f);
    #pragma unroll 8
    for (int r = r0; r < r1; ++r) {
        float4 v = xv[(size_t)(start + r) * CV + t];
        acc.x += v.x; acc.y += v.y; acc.z += v.z; acc.w += v.w;
    }
    ((float4*)P)[(size_t)bx * CV + t] = acc;
}

// ---------------- Pass 1b: reduce partials -> mean_t (transposed [C][NB]), cum ----------------
// grid = NB blocks, 128 threads
__global__ __launch_bounds__(128) void k_mean(const float* __restrict__ P,
                       const int* __restrict__ npoint,
                       float* __restrict__ mean_t,
                       int* __restrict__ cum) {
    int b = blockIdx.x;
    int t = threadIdx.x;
    const float4* Pv = (const float4*)P;
    float4 acc = make_float4(0.f, 0.f, 0.f, 0.f);
    #pragma unroll 8
    for (int rs = 0; rs < RS; ++rs) {
        float4 v = Pv[((size_t)(b * RS + rs)) * CV + t];
        acc.x += v.x; acc.y += v.y; acc.z += v.z; acc.w += v.w;
    }
    float inv = 1.0f / (float)npoint[b];
    int c = 4 * t;
    mean_t[(size_t)(c + 0) * NB + b] = acc.x * inv;
    mean_t[(size_t)(c + 1) * NB + b] = acc.y * inv;
    mean_t[(size_t)(c + 2) * NB + b] = acc.z * inv;
    mean_t[(size_t)(c + 3) * NB + b] = acc.w * inv;
    if (t == 0) {
        int s = 0;
        for (int i = 0; i <= b; ++i) s += npoint[i];
        cum[b] = s;
    }
}

// ---------------- FC1 + BN + ReLU (both branches), 8-way K-split ----------------
// grid = 2 * (MIDD/8) = 512 blocks, 512 threads (8 waves; lane = batch row)
// Side job: first 16384 global threads build segtab (per-k_final-block segment id).
__global__ __launch_bounds__(512) void k_fc1(const float* __restrict__ mean_t,
                                             const float* __restrict__ W1a,
                                             const float* __restrict__ g1a,
                                             const float* __restrict__ b1a,
                                             const float* __restrict__ W1b,
                                             const float* __restrict__ g1b,
                                             const float* __restrict__ b1b,
                                             const int* __restrict__ cum,
                                             unsigned char* __restrict__ segtab,
                                             float* __restrict__ h_t) {
    __shared__ float red[8][64][9];
    int bx = blockIdx.x;
    int branch = bx >> 8;            // 256 col-groups per branch
    int cg = bx & 255;
    int c0 = cg * 8;
    const float* W1 = branch ? W1b : W1a;
    const float* g  = branch ? g1b : g1a;
    const float* bb = branch ? b1b : b1a;
    int t = threadIdx.x;

    // segtab side job: one entry per k_final block of FROWS rows
    int gid = bx * 512 + t;
    if (gid < 16384) {
        int r0 = gid * FROWS;
        int lo = seg_search(cum, r0);
        int hi = seg_search(cum, r0 + FROWS - 1);
        segtab[gid] = (lo == hi) ? (unsigned char)lo : (unsigned char)255;
    }

    int lane = t & 63;               // batch row
    int w = t >> 6;                  // wave id = K-chunk = epilogue column
    float acc[8];
    #pragma unroll
    for (int i = 0; i < 8; ++i) acc[i] = 0.f;
    int k0 = w * 64;
    for (int k = k0; k < k0 + 64; ++k) {
        float mval = mean_t[(size_t)k * NB + lane];           // coalesced
        const float4* wr = (const float4*)(W1 + (size_t)k * MIDD + c0);
        float4 w0 = wr[0], w1 = wr[1];                        // broadcast
        acc[0] += mval * w0.x; acc[1] += mval * w0.y;
        acc[2] += mval * w0.z; acc[3] += mval * w0.w;
        acc[4] += mval * w1.x; acc[5] += mval * w1.y;
        acc[6] += mval * w1.z; acc[7] += mval * w1.w;
    }
    #pragma unroll
    for (int i = 0; i < 8; ++i) red[w][lane][i] = acc[i];
    __syncthreads();
    // epilogue: wave w owns column c0+w
    float v = red[0][lane][w];
    #pragma unroll
    for (int ww = 1; ww < 8; ++ww) v += red[ww][lane][w];
    float s = wave_sum64(v);
    float m = s * (1.0f / 64.0f);
    float d = v - m;
    float q = wave_sum64(d * d);
    float var = q * (1.0f / 64.0f);
    float val = fmaxf(d * rsqrtf(var + EPSV) * g[c0 + w] + bb[c0 + w], 0.0f);
    h_t[((size_t)branch * MIDD + c0 + w) * NB + lane] = val;  // coalesced
}

// ---------------- FC2 (+ReLU, +sigmoid for branch b), 8-way K-split ----------------
// grid = 2 * (CD/8) = 128 blocks, 512 threads
__global__ __launch_bounds__(512) void k_fc2(const float* __restrict__ h_t,
                                             const float* __restrict__ W2a,
                                             const float* __restrict__ W2b,
                                             float* __restrict__ out_mean,
                                             float* __restrict__ out_w) {
    __shared__ float red[8][64][9];
    int bx = blockIdx.x;
    int branch = bx >> 6;            // 64 col-groups per branch
    int cg = bx & 63;
    int c0 = cg * 8;
    const float* W2 = branch ? W2b : W2a;
    int t = threadIdx.x;
    int lane = t & 63;
    int w = t >> 6;
    float acc[8];
    #pragma unroll
    for (int i = 0; i < 8; ++i) acc[i] = 0.f;
    int k0 = w * 256;
    for (int k = k0; k < k0 + 256; ++k) {
        float hv = h_t[((size_t)branch * MIDD + k) * NB + lane];   // coalesced
        const float4* wr = (const float4*)(W2 + (size_t)k * CD + c0);
        float4 w0 = wr[0], w1 = wr[1];                             // broadcast
        acc[0] += hv * w0.x; acc[1] += hv * w0.y;
        acc[2] += hv * w0.z; acc[3] += hv * w0.w;
        acc[4] += hv * w1.x; acc[5] += hv * w1.y;
        acc[6] += hv * w1.z; acc[7] += hv * w1.w;
    }
    #pragma unroll
    for (int i = 0; i < 8; ++i) red[w][lane][i] = acc[i];
    __syncthreads();
    float v = red[0][lane][w];
    #pragma unroll
    for (int ww = 1; ww < 8; ++ww) v += red[ww][lane][w];
    float r = fmaxf(v, 0.0f);
    if (branch)
        out_w[(size_t)lane * CD + c0 + w] = 1.0f / (1.0f + expf(-r));
    else
        out_mean[(size_t)lane * CD + c0 + w] = r;
}

// ---------------- Final combine: R5 config (256thr, 8 fp4, reversed, nt stores) ----------------
// + segtab kills the 6-deep search chain: 1 hot byte load -> gathers immediately.
__global__ __launch_bounds__(256) void k_final(const float* __restrict__ x2,
                        const int* __restrict__ cum,
                        const unsigned char* __restrict__ segtab,
                        const float* __restrict__ out_mean,
                        const float* __restrict__ out_w,
                        float* __restrict__ out) {
    int t = threadIdx.x;
    int bx = (int)gridDim.x - 1 - (int)blockIdx.x;   // reversed
    size_t base = (size_t)bx << 11;                   // 2048 float4 per block
    int base_row = bx << 4;                           // 16 rows per block
    const fx4* xv = (const fx4*)x2;
    const fx4* wv = (const fx4*)out_w;
    const fx4* mv = (const fx4*)out_mean;
    fx4* ov = (fx4*)out;

    int stab = segtab[bx];           // single hot load, no chain

    // 8 independent x2 loads in flight while segtab resolves
    fx4 xs[FPT];
    #pragma unroll
    for (int k = 0; k < FPT; ++k)
        xs[k] = xv[base + ((size_t)k << 8) + t];

    int colv = t & 127;

    if (stab != 255) {               // block-uniform (16383/16384 blocks)
        fx4 ww = wv[(size_t)stab * CV + colv];
        fx4 mm = mv[(size_t)stab * CV + colv];
        fx4 a = ww * 0.5f + 0.75f;
        #pragma unroll
        for (int k = 0; k < FPT; ++k) {
            fx4 o = xs[k] * a + mm;
            __builtin_nontemporal_store(o, &ov[base + ((size_t)k << 8) + t]);
        }
    } else {                          // rare boundary block
        #pragma unroll
        for (int k = 0; k < FPT; ++k) {
            int row = base_row + ((k * 256 + t) >> 7);
            int seg = seg_search(cum, row);
            fx4 ww = wv[(size_t)seg * CV + colv];
            fx4 mm = mv[(size_t)seg * CV + colv];
            fx4 o = xs[k] * (ww * 0.5f + 0.75f) + mm;
            __builtin_nontemporal_store(o, &ov[base + ((size_t)k << 8) + t]);
        }
    }
}

extern "C" void kernel_launch(void* const* d_in, const int* in_sizes, int n_in,
                              void* d_out, int out_size, void* d_ws, size_t ws_size,
                              hipStream_t stream) {
    const float* x2  = (const float*)d_in[0];
    const int*   npt = (const int*)d_in[1];
    const float* W1a = (const float*)d_in[2];
    const float* g1a = (const float*)d_in[3];
    const float* b1a = (const float*)d_in[4];
    const float* W2a = (const float*)d_in[5];
    const float* W1b = (const float*)d_in[6];
    const float* g1b = (const float*)d_in[7];
    const float* b1b = (const float*)d_in[8];
    const float* W2b = (const float*)d_in[9];
    float* out = (float*)d_out;

    const int N   = in_sizes[0] / CD;      // 262144
    const int NC4 = (N * CD) / 4;          // total float4
    const int NFB = NC4 / (256 * FPT);     // k_final blocks = 16384

    // scratch: big dead-before-final arrays live in d_out
    float* P      = out;                              // [NB*RS*CD]    = 8 MB
    float* mean_t = out + (size_t)NB * RS * CD;       // [CD*NB]       = 128 KB (transposed)
    float* h_t    = mean_t + (size_t)NB * CD;         // [2*MIDD*NB]   = 1 MB (transposed)
    // small live-at-final arrays in ws
    int*   cum      = (int*)d_ws;                     // 64 ints
    float* out_mean = (float*)d_ws + 64;              // [NB*CD]
    float* out_w    = out_mean + (size_t)NB * CD;     // [NB*CD]
    unsigned char* segtab = (unsigned char*)(out_w + (size_t)NB * CD);  // [16384]

    k_partial<<<NB * RS, 128, 0, stream>>>(x2, npt, P);
    k_mean<<<NB, 128, 0, stream>>>(P, npt, mean_t, cum);
    k_fc1<<<2 * (MIDD / 8), 512, 0, stream>>>(mean_t, W1a, g1a, b1a, W1b, g1b, b1b, cum, segtab, h_t);
    k_fc2<<<2 * (CD / 8), 512, 0, stream>>>(h_t, W2a, W2b, out_mean, out_w);
    k_final<<<NFB, 256, 0, stream>>>(x2, cum, segtab, out_mean, out_w, out);
}